// Round 15
// baseline (811.653 us; speedup 1.0000x reference)
//
#include <hip/hip_runtime.h>
#include <stdint.h>

#define MDIM 8192
#define NDIM 16384
#define KDIM 4096
#define NT   64          // K-steps of 64
#define PSTR 1048576     // panel stride: 256 rows x 4096 k (bytes, i8)

typedef __attribute__((ext_vector_type(4)))  int i32x4;
typedef __attribute__((ext_vector_type(16))) int i32x16;

__device__ __forceinline__ void gload_lds16(const void* g, void* l) {
    __builtin_amdgcn_global_load_lds(
        (const __attribute__((address_space(1))) void*)g,
        (__attribute__((address_space(3))) void*)l,
        16, 0, 0);
}

__device__ __forceinline__ i32x16 MFMA32(i32x4 a, i32x4 b, i32x16 c) {
    return __builtin_amdgcn_mfma_i32_32x32x32_i8(a, b, c, 0, 0, 0);
}

// ---------------- quantization / relayout kernels ----------------
// ws layout (K-major panel-chunked, 256-row panels): elem (row,k) of panel p at
//   p*PSTR + (k>>6)*16384 + ((k>>4)&3)*4096 + (row&255)*16 + (k&15).

// pass 1: per-row absmax -> sx (dequant), invx (quant)
__global__ __launch_bounds__(256)
void rowmax_kernel(const float* __restrict__ x, float* __restrict__ sx,
                   float* __restrict__ invx) {
    const int row = (int)blockIdx.x;
    const float4* xr = (const float4*)(x + (long)row * KDIM);
    const int t = threadIdx.x;
    float m = 0.f;
#pragma unroll
    for (int i = 0; i < 4; ++i) {
        float4 v = xr[t + 256 * i];
        m = fmaxf(m, fmaxf(fmaxf(fabsf(v.x), fabsf(v.y)), fmaxf(fabsf(v.z), fabsf(v.w))));
    }
#pragma unroll
    for (int off = 32; off >= 1; off >>= 1) m = fmaxf(m, __shfl_xor(m, off));
    __shared__ float red[4];
    if ((t & 63) == 0) red[t >> 6] = m;
    __syncthreads();
    m = fmaxf(fmaxf(red[0], red[1]), fmaxf(red[2], red[3]));
    m = fmaxf(m, 1e-20f);
    if (t == 0) { sx[row] = m * (1.0f / 127.0f); invx[row] = 127.0f / m; }
}

// pass 2: quantize + transpose-to-K-major through LDS (coalesced both sides).
// block = (panel p, K-step tt): 256 rows x 64 k.
__global__ __launch_bounds__(256)
void quantx_t2(const float* __restrict__ x, const float* __restrict__ invx,
               int8_t* __restrict__ xq) {
    __shared__ int4 tb[1024];   // K-major: tb[c*256 + row]
    const int b = (int)blockIdx.x;
    const int p = b >> 6, tt = b & 63;
    const int tid = threadIdx.x;
#pragma unroll
    for (int i = 0; i < 4; ++i) {
        const int idx = i * 256 + tid;
        const int row = idx >> 2, c = idx & 3;
        const float inv = invx[p * 256 + row];
        const float4* src = (const float4*)(x + ((long)p * 256 + row) * KDIM + tt * 64 + c * 16);
        union { int8_t ch[16]; int4 v; } r;
#pragma unroll
        for (int j = 0; j < 4; ++j) {
            float4 v = src[j];
            r.ch[j * 4 + 0] = (int8_t)__float2int_rn(v.x * inv);
            r.ch[j * 4 + 1] = (int8_t)__float2int_rn(v.y * inv);
            r.ch[j * 4 + 2] = (int8_t)__float2int_rn(v.z * inv);
            r.ch[j * 4 + 3] = (int8_t)__float2int_rn(v.w * inv);
        }
        tb[c * 256 + row] = r.v;
    }
    __syncthreads();
    int4* dst = (int4*)(xq + (long)p * PSTR + (long)tt * 16384);
#pragma unroll
    for (int i = 0; i < 4; ++i) {
        const int idx = i * 256 + tid;
        dst[idx] = tb[idx];
    }
}

// W: (q-zp) in [-15,15] -> int8 EXACT, transpose-to-K-major through LDS.
__global__ __launch_bounds__(256)
void quantw_t2(const int* __restrict__ q, const int* __restrict__ zp,
               int8_t* __restrict__ wq) {
    __shared__ int4 tb[1024];
    const int b = (int)blockIdx.x;
    const int p = b >> 6, tt = b & 63;
    const int tid = threadIdx.x;
#pragma unroll
    for (int i = 0; i < 4; ++i) {
        const int idx = i * 256 + tid;
        const int row = idx >> 2, c = idx & 3;
        const int z = zp[p * 256 + row];
        const int4* src = (const int4*)(q + ((long)p * 256 + row) * KDIM + tt * 64 + c * 16);
        union { int8_t ch[16]; int4 v; } r;
#pragma unroll
        for (int j = 0; j < 4; ++j) {
            int4 a = src[j];
            r.ch[j * 4 + 0] = (int8_t)(a.x - z);
            r.ch[j * 4 + 1] = (int8_t)(a.y - z);
            r.ch[j * 4 + 2] = (int8_t)(a.z - z);
            r.ch[j * 4 + 3] = (int8_t)(a.w - z);
        }
        tb[c * 256 + row] = r.v;
    }
    __syncthreads();
    int4* dst = (int4*)(wq + (long)p * PSTR + (long)tt * 16384);
#pragma unroll
    for (int i = 0; i < 4; ++i) {
        const int idx = i * 256 + tid;
        dst[idx] = tb[idx];
    }
}

// ---- 128x128 4-wave int8 GEMM, 32x32x32 MFMA, K-major LDS, 2 BLOCKS/CU ----
// C[m,n] = scale[n] * sx[m] * sum_k xq[m,k] * wq[n,k]   (i32 accum, exact)
// acc = 64 VGPR/wave (wave tile 64x64) -> fits the 128-VGPR cap that 2
// blocks/CU requires (round-9 failure mode fixed arithmetically).
// LDS: 2 bufs x (A 8 KB + B 8 KB) = 32 KB/block -> 2 blocks/CU.
// Cross-block overlap (m114/m97): while this block sits in the vmcnt(0)+
// barrier drain, the co-resident block's waves feed the MFMA pipe.
// Plane = [4 chunks][128 rows][16 B] K-major: frag reads = 512 B contiguous
// per half-wave (conflict-free, round-14-verified); staging = 4 linear lines.
// Loop = round-8's race-free drain loop (verified absmax 28 there).
// No sched_barrier fences: compiler emits fine-grained lgkm (m97 evidence).
// Block mapping: 512 concurrent blocks (2/CU) cover ALL 64 A-panels x 8
// B-panels; A (33 MB) L3-resident; A-panel sharers on one XCD (ii%8==bm2%8).

__global__ __launch_bounds__(256, 2)
void gemm_i8_kernel(const int8_t* __restrict__ A, const int8_t* __restrict__ Wt,
                    const float* __restrict__ scale, const float* __restrict__ sx,
                    float* __restrict__ C) {
    __shared__ int8_t lds[2][16384];

    const int wg  = (int)blockIdx.x;
    const int rr  = wg >> 9;                  // round 0..15
    const int ii  = wg & 511;
    const int bm2 = ii & 63;                  // 0..63 (all A-panels each round)
    const int bn2 = rr * 8 + (ii >> 6);       // 0..127 (8 fresh B-panels/round)

    const int tid  = threadIdx.x;
    const int lane = tid & 63;
    const int wid  = tid >> 6;                // 0..3
    const int wm   = wid >> 1;                // 0..1 (64 rows)
    const int wn   = wid & 1;                 // 0..1 (64 cols)
    const int l31  = lane & 31;
    const int lh   = lane >> 5;               // 0..1

    // frag base offsets within a buffer (A plane at 0, B plane at +8192)
    const int fA = lh * 2048 + (wm * 64 + l31) * 16;
    const int fB = 8192 + lh * 2048 + (wn * 64 + l31) * 16;
    // read addr: buf + fA + ks*4096 + mt*512   (chunk = ks*2+lh; mt*32 rows)

    // staging: A plane = 512 slots of 16 B; slot s: chunk=s>>7, row=s&127.
    const int s0 = tid, s1 = tid + 256;
    const int g0 = (s0 >> 7) * 4096 + (s0 & 127) * 16;
    const int g1 = (s1 >> 7) * 4096 + (s1 & 127) * 16;

    const int8_t* pA = A  + (long)(bm2 >> 1) * PSTR + (bm2 & 1) * 2048;
    const int8_t* pB = Wt + (long)(bn2 >> 1) * PSTR + (bn2 & 1) * 2048;

#define STAGE(BUF, TT)                                                              \
    do {                                                                            \
        const int ko_ = (TT) * 16384;                                               \
        gload_lds16(pA + ko_ + g0, &lds[BUF][s0 * 16]);                             \
        gload_lds16(pA + ko_ + g1, &lds[BUF][s1 * 16]);                             \
        gload_lds16(pB + ko_ + g0, &lds[BUF][8192 + s0 * 16]);                      \
        gload_lds16(pB + ko_ + g1, &lds[BUF][8192 + s1 * 16]);                      \
    } while (0)

    i32x16 acc[2][2];
#pragma unroll
    for (int i = 0; i < 2; ++i)
#pragma unroll
        for (int j = 0; j < 2; ++j)
#pragma unroll
            for (int r = 0; r < 16; ++r) acc[i][j][r] = 0;

    // prologue
    STAGE(0, 0);
    asm volatile("s_waitcnt vmcnt(0)" ::: "memory");
    __builtin_amdgcn_s_barrier();

    for (int t = 0; t < NT; ++t) {
        const int cur = t & 1;
        const bool pf = (t + 1 < NT);
        if (pf) STAGE(cur ^ 1, t + 1);

        i32x4 aF[4], bF[4];
#pragma unroll
        for (int mt = 0; mt < 2; ++mt)
#pragma unroll
            for (int ks = 0; ks < 2; ++ks)
                aF[mt * 2 + ks] = *(const i32x4*)&lds[cur][fA + ks * 4096 + mt * 512];
#pragma unroll
        for (int nt = 0; nt < 2; ++nt)
#pragma unroll
            for (int ks = 0; ks < 2; ++ks)
                bF[nt * 2 + ks] = *(const i32x4*)&lds[cur][fB + ks * 4096 + nt * 512];

        __builtin_amdgcn_s_setprio(1);
#pragma unroll
        for (int mt = 0; mt < 2; ++mt)
#pragma unroll
            for (int nt = 0; nt < 2; ++nt)
#pragma unroll
                for (int ks = 0; ks < 2; ++ks)
                    acc[mt][nt] = MFMA32(aF[mt * 2 + ks], bF[nt * 2 + ks], acc[mt][nt]);
        __builtin_amdgcn_s_setprio(0);

        asm volatile("s_waitcnt lgkmcnt(0)" ::: "memory");   // WAR: reads of cur done
        if (pf) asm volatile("s_waitcnt vmcnt(0)" ::: "memory"); // t+1 landed
        __builtin_amdgcn_s_barrier();
    }
#undef STAGE

    // epilogue: 32x32 D mapping (m74/m101; rounds 13-14 verified):
    // col = lane&31, row = (reg&3) + 8*(reg>>2) + 4*(lane>>5)
    const long rowA0 = (long)bm2 * 128 + wm * 64;
    const int  colB0 = bn2 * 128 + wn * 64;
    float scj[2];
#pragma unroll
    for (int n = 0; n < 2; ++n) scj[n] = scale[colB0 + n * 32 + l31];
#pragma unroll
    for (int mt = 0; mt < 2; ++mt) {
#pragma unroll
        for (int g = 0; g < 4; ++g) {
            const long rb = rowA0 + mt * 32 + g * 8 + lh * 4;
            const float4 s4 = *(const float4*)(sx + rb);
#pragma unroll
            for (int n = 0; n < 2; ++n) {
                float* cp = C + rb * NDIM + colB0 + n * 32 + l31;
                cp[0 * (long)NDIM] = (float)acc[mt][n][g * 4 + 0] * scj[n] * s4.x;
                cp[1 * (long)NDIM] = (float)acc[mt][n][g * 4 + 1] * scj[n] * s4.y;
                cp[2 * (long)NDIM] = (float)acc[mt][n][g * 4 + 2] * scj[n] * s4.z;
                cp[3 * (long)NDIM] = (float)acc[mt][n][g * 4 + 3] * scj[n] * s4.w;
            }
        }
    }
}

// ---------------- safety fallback (no workspace needed, fp32, slow) ----------------

__global__ __launch_bounds__(256)
void fallback_kernel(const float* __restrict__ x, const int* __restrict__ q,
                     const float* __restrict__ scale, const int* __restrict__ zp,
                     float* __restrict__ out) {
    __shared__ float sA[64][17];
    __shared__ float sB[64][17];
    const int bn = (int)blockIdx.x % (NDIM / 64);
    const int bm = (int)blockIdx.x / (NDIM / 64);
    const int t  = threadIdx.x;
    const int tx = t & 15, ty = t >> 4;
    const long rowA = (long)bm * 64, rowB = (long)bn * 64;
    float acc[4][4] = {};
    for (int k0 = 0; k0 < KDIM; k0 += 16) {
#pragma unroll
        for (int i = 0; i < 4; ++i) {
            const int e = t + i * 256;
            const int r = e >> 4, c = e & 15;
            sA[r][c] = x[(rowA + r) * KDIM + k0 + c];
            const int o = (int)rowB + r;
            sB[r][c] = (float)(q[(long)o * KDIM + k0 + c] - zp[o]) * scale[o];
        }
        __syncthreads();
#pragma unroll
        for (int kk = 0; kk < 16; ++kk) {
            float a[4], b[4];
#pragma unroll
            for (int i = 0; i < 4; ++i) a[i] = sA[ty * 4 + i][kk];
#pragma unroll
            for (int j = 0; j < 4; ++j) b[j] = sB[tx * 4 + j][kk];
#pragma unroll
            for (int i = 0; i < 4; ++i)
#pragma unroll
                for (int j = 0; j < 4; ++j) acc[i][j] += a[i] * b[j];
        }
        __syncthreads();
    }
#pragma unroll
    for (int i = 0; i < 4; ++i) {
        const long r = rowA + ty * 4 + i;
#pragma unroll
        for (int j = 0; j < 4; ++j)
            out[r * NDIM + rowB + tx * 4 + j] = acc[i][j];
    }
}

// ---------------- launch ----------------

extern "C" void kernel_launch(void* const* d_in, const int* in_sizes, int n_in,
                              void* d_out, int out_size, void* d_ws, size_t ws_size,
                              hipStream_t stream) {
    const float* x     = (const float*)d_in[0];
    const int*   qw    = (const int*)d_in[1];
    const float* scale = (const float*)d_in[2];
    const int*   zp    = (const int*)d_in[3];
    float*       out   = (float*)d_out;

    const size_t needA  = (size_t)MDIM * KDIM;          // 33.5 MB int8
    const size_t needW  = (size_t)NDIM * KDIM;          // 67.1 MB int8
    const size_t needSx = (size_t)MDIM * sizeof(float); // 32 KB
    const size_t needIx = (size_t)MDIM * sizeof(float); // 32 KB

    if (ws_size >= needA + needW + needSx + needIx) {
        int8_t* xq = (int8_t*)d_ws;
        int8_t* wq = xq + needA;
        float*  sx = (float*)((char*)d_ws + needA + needW);
        float*  ix = sx + MDIM;
        rowmax_kernel<<<MDIM, 256, 0, stream>>>(x, sx, ix);
        quantx_t2<<<(MDIM / 256) * 64, 256, 0, stream>>>(x, ix, xq);
        quantw_t2<<<(NDIM / 256) * 64, 256, 0, stream>>>(qw, zp, wq);
        gemm_i8_kernel<<<(MDIM / 128) * (NDIM / 128), 256, 0, stream>>>(xq, wq, scale, sx, out);
    } else {
        fallback_kernel<<<(MDIM / 64) * (NDIM / 64), 256, 0, stream>>>(x, qw, scale, zp, out);
    }
}

// Round 16
// 801.752 us; speedup vs baseline: 1.0123x; 1.0123x over previous
//
#include <hip/hip_runtime.h>
#include <stdint.h>

#define MDIM 8192
#define NDIM 16384
#define KDIM 4096
#define NT   64          // K-steps of 64
#define PSTR 1048576     // panel stride: 256 rows x 4096 k (bytes, i8)

typedef __attribute__((ext_vector_type(4)))  int i32x4;
typedef __attribute__((ext_vector_type(16))) int i32x16;

__device__ __forceinline__ i32x16 MFMA32(i32x4 a, i32x4 b, i32x16 c) {
    return __builtin_amdgcn_mfma_i32_32x32x32_i8(a, b, c, 0, 0, 0);
}

// ---------------- quantization / relayout kernels (round-14/15 verified) ----------------
// ws layout (K-major panel-chunked, 256-row panels): elem (row,k) of panel p at
//   p*PSTR + (k>>6)*16384 + ((k>>4)&3)*4096 + (row&255)*16 + (k&15).

__global__ __launch_bounds__(256)
void rowmax_kernel(const float* __restrict__ x, float* __restrict__ sx,
                   float* __restrict__ invx) {
    const int row = (int)blockIdx.x;
    const float4* xr = (const float4*)(x + (long)row * KDIM);
    const int t = threadIdx.x;
    float m = 0.f;
#pragma unroll
    for (int i = 0; i < 4; ++i) {
        float4 v = xr[t + 256 * i];
        m = fmaxf(m, fmaxf(fmaxf(fabsf(v.x), fabsf(v.y)), fmaxf(fabsf(v.z), fabsf(v.w))));
    }
#pragma unroll
    for (int off = 32; off >= 1; off >>= 1) m = fmaxf(m, __shfl_xor(m, off));
    __shared__ float red[4];
    if ((t & 63) == 0) red[t >> 6] = m;
    __syncthreads();
    m = fmaxf(fmaxf(red[0], red[1]), fmaxf(red[2], red[3]));
    m = fmaxf(m, 1e-20f);
    if (t == 0) { sx[row] = m * (1.0f / 127.0f); invx[row] = 127.0f / m; }
}

__global__ __launch_bounds__(256)
void quantx_t2(const float* __restrict__ x, const float* __restrict__ invx,
               int8_t* __restrict__ xq) {
    __shared__ int4 tb[1024];   // K-major: tb[c*256 + row]
    const int b = (int)blockIdx.x;
    const int p = b >> 6, tt = b & 63;
    const int tid = threadIdx.x;
#pragma unroll
    for (int i = 0; i < 4; ++i) {
        const int idx = i * 256 + tid;
        const int row = idx >> 2, c = idx & 3;
        const float inv = invx[p * 256 + row];
        const float4* src = (const float4*)(x + ((long)p * 256 + row) * KDIM + tt * 64 + c * 16);
        union { int8_t ch[16]; int4 v; } r;
#pragma unroll
        for (int j = 0; j < 4; ++j) {
            float4 v = src[j];
            r.ch[j * 4 + 0] = (int8_t)__float2int_rn(v.x * inv);
            r.ch[j * 4 + 1] = (int8_t)__float2int_rn(v.y * inv);
            r.ch[j * 4 + 2] = (int8_t)__float2int_rn(v.z * inv);
            r.ch[j * 4 + 3] = (int8_t)__float2int_rn(v.w * inv);
        }
        tb[c * 256 + row] = r.v;
    }
    __syncthreads();
    int4* dst = (int4*)(xq + (long)p * PSTR + (long)tt * 16384);
#pragma unroll
    for (int i = 0; i < 4; ++i) {
        const int idx = i * 256 + tid;
        dst[idx] = tb[idx];
    }
}

__global__ __launch_bounds__(256)
void quantw_t2(const int* __restrict__ q, const int* __restrict__ zp,
               int8_t* __restrict__ wq) {
    __shared__ int4 tb[1024];
    const int b = (int)blockIdx.x;
    const int p = b >> 6, tt = b & 63;
    const int tid = threadIdx.x;
#pragma unroll
    for (int i = 0; i < 4; ++i) {
        const int idx = i * 256 + tid;
        const int row = idx >> 2, c = idx & 3;
        const int z = zp[p * 256 + row];
        const int4* src = (const int4*)(q + ((long)p * 256 + row) * KDIM + tt * 64 + c * 16);
        union { int8_t ch[16]; int4 v; } r;
#pragma unroll
        for (int j = 0; j < 4; ++j) {
            int4 a = src[j];
            r.ch[j * 4 + 0] = (int8_t)(a.x - z);
            r.ch[j * 4 + 1] = (int8_t)(a.y - z);
            r.ch[j * 4 + 2] = (int8_t)(a.z - z);
            r.ch[j * 4 + 3] = (int8_t)(a.w - z);
        }
        tb[c * 256 + row] = r.v;
    }
    __syncthreads();
    int4* dst = (int4*)(wq + (long)p * PSTR + (long)tt * 16384);
#pragma unroll
    for (int i = 0; i < 4; ++i) {
        const int idx = i * 256 + tid;
        dst[idx] = tb[idx];
    }
}

// ---- 256x256 8-wave int8 GEMM: NO-LDS, ZERO-BARRIER, register-direct frags ----
// C[m,n] = scale[n] * sx[m] * sum_k xq[m,k] * wq[n,k]   (i32 accum, exact)
// Mechanism shift (rounds 6-15 all ~45% MfmaUtil: LDS reads + MFMA serialize
// under barrier-lockstep): with K-major global layout a fragment load is 32
// lanes x 16 B CONTIGUOUS -> load frags straight to registers. No LDS, no
// s_barrier in the K-loop; each wave is an independent load->MFMA stream; the
// 2 waves/SIMD co-schedule (m114: time = max, not sum); frag sets double-
// buffered, compiler emits counted vmcnt (m97 evidence).
// Cache: per-K-step unique bytes/block = A 16 KB + B 8 KB = 24 KB < 32 KB L1
// -> duplicate A-reads (4 waves/wm) L1-served; L2 sees ~3 GB total; inputs
// (100 MB) L3-resident; A panels XCD-pinned (round-3 mapping).
// Wave tile 128x64: acc 4x2 x i32x16 = 128 VGPR; 2 frag sets = 96; ~245 total
// under the 256 cap of __launch_bounds__(512,2).
// Epilogue: 32x32 D mapping col=lane&31, row=(reg&3)+8*(reg>>2)+4*(lane>>5)
// (m74/m101; rounds 13-15 absmax-28-verified).

__global__ __launch_bounds__(512, 2)
void gemm_i8_kernel(const int8_t* __restrict__ A, const int8_t* __restrict__ Wt,
                    const float* __restrict__ scale, const float* __restrict__ sx,
                    float* __restrict__ C) {
    const int wg = (int)blockIdx.x;
    const int rr = wg >> 8;                   // round 0..7
    const int ii = wg & 255;
    const int bm = ii & 31;                   // all 32 A-panels each round
    const int bn = rr * 8 + (ii >> 5);        // 8 fresh B-panels per round

    const int tid  = threadIdx.x;
    const int lane = tid & 63;
    const int wid  = tid >> 6;
    const int wm   = wid >> 2;        // 0..1 (128 rows)
    const int wn   = wid & 3;         // 0..3 (64 cols)
    const int l31  = lane & 31;
    const int lh   = lane >> 5;       // 0..1

    // frag addresses (K-major): elem(row, chunk) at chunk*4096 + row*16 within
    // a K-step block of 16384 B. chunk = ks*2 + lh.
    const int aoff = lh * 4096 + (wm * 128 + l31) * 16;   // + mt*512 + ks*8192
    const int boff = lh * 4096 + (wn * 64 + l31) * 16;    // + nt*512 + ks*8192

    const int8_t* pA = A  + (long)bm * PSTR;
    const int8_t* pB = Wt + (long)bn * PSTR;

// load one K-step's fragments for this wave: A 4x2 + B 2x2 = 12 x dwordx4
#define LOADF(AS, BS, TT)                                                           \
    do {                                                                            \
        const int8_t* bA_ = pA + (TT) * 16384;                                      \
        const int8_t* bB_ = pB + (TT) * 16384;                                      \
        _Pragma("unroll")                                                           \
        for (int mt_ = 0; mt_ < 4; ++mt_)                                           \
            _Pragma("unroll")                                                       \
            for (int ks_ = 0; ks_ < 2; ++ks_)                                       \
                AS[mt_ * 2 + ks_] =                                                 \
                    *(const i32x4*)(bA_ + ks_ * 8192 + mt_ * 512 + aoff);           \
        _Pragma("unroll")                                                           \
        for (int nt_ = 0; nt_ < 2; ++nt_)                                           \
            _Pragma("unroll")                                                       \
            for (int ks_ = 0; ks_ < 2; ++ks_)                                       \
                BS[nt_ * 2 + ks_] =                                                 \
                    *(const i32x4*)(bB_ + ks_ * 8192 + nt_ * 512 + boff);           \
    } while (0)

// 16 MFMA: 4 m-tiles x 2 n-tiles x 2 ks
#define MFMAALL(AS, BS)                                                             \
    _Pragma("unroll")                                                               \
    for (int mt_ = 0; mt_ < 4; ++mt_)                                               \
        _Pragma("unroll")                                                           \
        for (int nt_ = 0; nt_ < 2; ++nt_)                                           \
            _Pragma("unroll")                                                       \
            for (int ks_ = 0; ks_ < 2; ++ks_)                                       \
                acc[mt_][nt_] = MFMA32(AS[mt_ * 2 + ks_], BS[nt_ * 2 + ks_],        \
                                       acc[mt_][nt_]);

    i32x16 acc[4][2];
#pragma unroll
    for (int i = 0; i < 4; ++i)
#pragma unroll
        for (int j = 0; j < 2; ++j)
#pragma unroll
            for (int r = 0; r < 16; ++r) acc[i][j][r] = 0;

    i32x4 aA[8], bA4[4], aB[8], bB4[4];

    // prologue: two K-steps in flight
    LOADF(aA, bA4, 0);
    LOADF(aB, bB4, 1);

    for (int t = 0; t < NT; t += 2) {
        MFMAALL(aA, bA4);                       // compiler waits set-A (vmcnt counted)
        if (t + 2 < NT) LOADF(aA, bA4, t + 2);  // refill under set-B's MFMAs
        MFMAALL(aB, bB4);
        if (t + 3 < NT) LOADF(aB, bB4, t + 3);
    }
#undef LOADF
#undef MFMAALL

    // epilogue: 32x32 D mapping (m74/m101; rounds 13-15 verified)
    const long rowA0 = (long)bm * 256 + wm * 128;
    const int  colB0 = bn * 256 + wn * 64;
    float scj[2];
#pragma unroll
    for (int n = 0; n < 2; ++n) scj[n] = scale[colB0 + n * 32 + l31];
#pragma unroll
    for (int mt = 0; mt < 4; ++mt) {
#pragma unroll
        for (int g = 0; g < 4; ++g) {
            const long rb = rowA0 + mt * 32 + g * 8 + lh * 4;
            const float4 s4 = *(const float4*)(sx + rb);
#pragma unroll
            for (int n = 0; n < 2; ++n) {
                float* cp = C + rb * NDIM + colB0 + n * 32 + l31;
                cp[0 * (long)NDIM] = (float)acc[mt][n][g * 4 + 0] * scj[n] * s4.x;
                cp[1 * (long)NDIM] = (float)acc[mt][n][g * 4 + 1] * scj[n] * s4.y;
                cp[2 * (long)NDIM] = (float)acc[mt][n][g * 4 + 2] * scj[n] * s4.z;
                cp[3 * (long)NDIM] = (float)acc[mt][n][g * 4 + 3] * scj[n] * s4.w;
            }
        }
    }
}

// ---------------- safety fallback (no workspace needed, fp32, slow) ----------------

__global__ __launch_bounds__(256)
void fallback_kernel(const float* __restrict__ x, const int* __restrict__ q,
                     const float* __restrict__ scale, const int* __restrict__ zp,
                     float* __restrict__ out) {
    __shared__ float sA[64][17];
    __shared__ float sB[64][17];
    const int bn = (int)blockIdx.x % (NDIM / 64);
    const int bm = (int)blockIdx.x / (NDIM / 64);
    const int t  = threadIdx.x;
    const int tx = t & 15, ty = t >> 4;
    const long rowA = (long)bm * 64, rowB = (long)bn * 64;
    float acc[4][4] = {};
    for (int k0 = 0; k0 < KDIM; k0 += 16) {
#pragma unroll
        for (int i = 0; i < 4; ++i) {
            const int e = t + i * 256;
            const int r = e >> 4, c = e & 15;
            sA[r][c] = x[(rowA + r) * KDIM + k0 + c];
            const int o = (int)rowB + r;
            sB[r][c] = (float)(q[(long)o * KDIM + k0 + c] - zp[o]) * scale[o];
        }
        __syncthreads();
#pragma unroll
        for (int kk = 0; kk < 16; ++kk) {
            float a[4], b[4];
#pragma unroll
            for (int i = 0; i < 4; ++i) a[i] = sA[ty * 4 + i][kk];
#pragma unroll
            for (int j = 0; j < 4; ++j) b[j] = sB[tx * 4 + j][kk];
#pragma unroll
            for (int i = 0; i < 4; ++i)
#pragma unroll
                for (int j = 0; j < 4; ++j) acc[i][j] += a[i] * b[j];
        }
        __syncthreads();
    }
#pragma unroll
    for (int i = 0; i < 4; ++i) {
        const long r = rowA + ty * 4 + i;
#pragma unroll
        for (int j = 0; j < 4; ++j)
            out[r * NDIM + rowB + tx * 4 + j] = acc[i][j];
    }
}

// ---------------- launch ----------------

extern "C" void kernel_launch(void* const* d_in, const int* in_sizes, int n_in,
                              void* d_out, int out_size, void* d_ws, size_t ws_size,
                              hipStream_t stream) {
    const float* x     = (const float*)d_in[0];
    const int*   qw    = (const int*)d_in[1];
    const float* scale = (const float*)d_in[2];
    const int*   zp    = (const int*)d_in[3];
    float*       out   = (float*)d_out;

    const size_t needA  = (size_t)MDIM * KDIM;          // 33.5 MB int8
    const size_t needW  = (size_t)NDIM * KDIM;          // 67.1 MB int8
    const size_t needSx = (size_t)MDIM * sizeof(float); // 32 KB
    const size_t needIx = (size_t)MDIM * sizeof(float); // 32 KB

    if (ws_size >= needA + needW + needSx + needIx) {
        int8_t* xq = (int8_t*)d_ws;
        int8_t* wq = xq + needA;
        float*  sx = (float*)((char*)d_ws + needA + needW);
        float*  ix = sx + MDIM;
        rowmax_kernel<<<MDIM, 256, 0, stream>>>(x, sx, ix);
        quantx_t2<<<(MDIM / 256) * 64, 256, 0, stream>>>(x, ix, xq);
        quantw_t2<<<(NDIM / 256) * 64, 256, 0, stream>>>(qw, zp, wq);
        gemm_i8_kernel<<<(MDIM / 256) * (NDIM / 256), 512, 0, stream>>>(xq, wq, scale, sx, out);
    } else {
        fallback_kernel<<<(MDIM / 64) * (NDIM / 64), 256, 0, stream>>>(x, qw, scale, zp, out);
    }
}

// Round 17
// 678.364 us; speedup vs baseline: 1.1965x; 1.1819x over previous
//
#include <hip/hip_runtime.h>
#include <stdint.h>

#define MDIM 8192
#define NDIM 16384
#define KDIM 4096
#define NT   64          // K-steps of 64

typedef __attribute__((ext_vector_type(4))) int i32x4;

__device__ __forceinline__ void gload_lds16(const void* g, void* l) {
    __builtin_amdgcn_global_load_lds(
        (const __attribute__((address_space(1))) void*)g,
        (__attribute__((address_space(3))) void*)l,
        16, 0, 0);
}

__device__ __forceinline__ i32x4 MFMA8(i32x4 a, i32x4 b, i32x4 c) {
    return __builtin_amdgcn_mfma_i32_16x16x64_i8(a, b, c, 0, 0, 0);
}

// ---------------- quantization kernels (round-6 verified) ----------------

__global__ __launch_bounds__(256)
void quant_x_kernel(const float* __restrict__ x, int8_t* __restrict__ xq,
                    float* __restrict__ sx) {
    const int row = (int)blockIdx.x;
    const float* xr = x + (long)row * KDIM;
    const int t = threadIdx.x;
    float v[16];
#pragma unroll
    for (int i = 0; i < 4; ++i)
        *(float4*)&v[i * 4] = ((const float4*)xr)[t + 256 * i];
    float m = 0.f;
#pragma unroll
    for (int i = 0; i < 16; ++i) m = fmaxf(m, fabsf(v[i]));
#pragma unroll
    for (int off = 32; off >= 1; off >>= 1) m = fmaxf(m, __shfl_xor(m, off));
    __shared__ float red[4];
    if ((t & 63) == 0) red[t >> 6] = m;
    __syncthreads();
    m = fmaxf(fmaxf(red[0], red[1]), fmaxf(red[2], red[3]));
    m = fmaxf(m, 1e-20f);
    const float inv = 127.0f / m;
    if (t == 0) sx[row] = m * (1.0f / 127.0f);
    int* qo = (int*)(xq + (long)row * KDIM);
#pragma unroll
    for (int i = 0; i < 4; ++i) {
        union { int8_t c[4]; int w; } o;
#pragma unroll
        for (int j = 0; j < 4; ++j)
            o.c[j] = (int8_t)__float2int_rn(v[i * 4 + j] * inv);
        qo[t + 256 * i] = o.w;
    }
}

__global__ __launch_bounds__(256)
void quant_w_kernel(const int* __restrict__ q, const int* __restrict__ zp,
                    int8_t* __restrict__ wq) {
    const long i = (long)blockIdx.x * 256 + threadIdx.x;
    const long e = i * 16;
    const int o = (int)(e >> 12);          // KDIM = 4096
    const int z = zp[o];
    union { int8_t c[16]; int4 v; } r;
#pragma unroll
    for (int b = 0; b < 4; ++b) {
        int4 a = ((const int4*)(q + e))[b];
        r.c[b * 4 + 0] = (int8_t)(a.x - z);
        r.c[b * 4 + 1] = (int8_t)(a.y - z);
        r.c[b * 4 + 2] = (int8_t)(a.z - z);
        r.c[b * 4 + 3] = (int8_t)(a.w - z);
    }
    *(int4*)(wq + e) = r.v;
}

// --- 256x256 8-wave int8 GEMM: 3-buf, 4-phase/K-tile, ONE counted vmcnt(4)/tile ---
// (round-10 configuration: best measured, 678.75 us total / ~562 us GEMM)
// C[m,n] = scale[n] * sx[m] * sum_k xq[m,k] * wq[n,k]   (i32 accum, exact)
// LDS: 3 bufs x 32 KB. Buf layout: Ah0[0,8K) Ah1[8K,16K) Bh0[16K,24K) Bh1[24K,32K);
// each half-plane (128r x 64B) = ONE gload_lds line (512 thr x 16 B).
// XOR chunk swizzle sc = c ^ ((r>>1)&3) via pre-swizzled global source, linear
// DMA dest (SQ_LDS_BANK_CONFLICT = 0, absmax 28, verified rounds 6/7/10/11/12).
//
// Per tile t (buf cb=t%3), 4 phases:
//   ph0: read aLo(4)+bLo(2); stage Ah0(t+2)->fb;          bar; lgkm0; 8 MFMA q(0,0)
//   ph1: read aHi(4);        stage Bh0(t+2)->fb;          bar; lgkm0; 8 MFMA q(4,0)
//   ph2: read bHi(2);        stage Ah1(t+2)->fb;          bar; lgkm0; 8 MFMA q(0,2)
//   ph3:                     stage Bh1(t+2)->fb; vmcnt(4);bar;        8 MFMA q(4,2)
// RAW LEDGER (1 load/phase/wave, fixed order): vmcnt(4) at ph3(t-1) leaves only
// tile t+1's 4 stages outstanding => tile t FULLY landed before ph0(t).
// Prologue: 8 loads (tiles 0,1), vmcnt(4) => tile 0 landed. WAR: region staged
// at ph_k(t) was last read ph_k(t-1), drained by that lgkm(0); >=1 barrier
// before the DMA issues. Tail: clamped dummy stages keep the ledger uniform.
//
// Block mapping (round-3 verified: FETCH 2.5 GB -> 0.39 GB): round = 256
// concurrent blocks covers ALL 32 A-panels x 8 B-panels; inputs L3-resident.
//
// PLATEAU NOTE (rounds 6-16): per K-tile per CU = MFMA ~1165-1306 cy +
// LDS-read ~1150 cy + sync ~300 cy, SERIAL (measured 2620 cy, all variants
// within 3%). Schedule surgery, wave-stagger, occupancy=2, 32x32 MFMA,
// K-major LDS, and no-LDS global-direct all null or regress. Breaking the
// serial sum needs hand-asm-grade interleave (AITER/HK territory).

__global__ __launch_bounds__(512, 2)
void gemm_i8_kernel(const int8_t* __restrict__ A, const int8_t* __restrict__ Wt,
                    const float* __restrict__ scale, const float* __restrict__ sx,
                    float* __restrict__ C) {
    __shared__ int8_t lds[3 * 32768];

    const int wg = (int)blockIdx.x;
    const int rr = wg >> 8;                   // round 0..7
    const int ii = wg & 255;
    const int bm = ii & 31;                   // all 32 A-panels each round
    const int bn = rr * 8 + (ii >> 5);        // 8 fresh B-panels per round

    const int tid  = threadIdx.x;
    const int lane = tid & 63;
    const int wid  = tid >> 6;
    const int wm   = wid >> 2;        // 0..1 (128 rows)
    const int wn   = wid & 3;         // 0..3 (64 cols)
    const int l15  = lane & 15;
    const int c16  = lane >> 4;       // 0..3 = logical k-chunk (16 i8)

    // fragment byte offset within a 16-KB plane (A at +0, B at +16384)
    const int axor = (l15 >> 1) & 3;
    const int fro  = l15 * 64 + ((c16 ^ axor) << 4);

    // staging: one line covers 128 rows x 64 B; thread tid -> row tid>>2,
    // phys chunk tid&3, global logical chunk (tid&3)^((tid>>3)&3)
    const int soff = (tid >> 2) * KDIM + ((((tid & 3) ^ ((tid >> 3) & 3))) << 4);
    const int dl   = tid * 16;

    const int8_t* Ab  = A  + (long)bm * 256 * KDIM;
    const int8_t* Wb  = Wt + (long)bn * 256 * KDIM;
    const int8_t* Ab2 = Ab + (long)128 * KDIM;
    const int8_t* Wb2 = Wb + (long)128 * KDIM;

#define STG(DSTB, SRC, TT) gload_lds16((SRC) + soff + (TT) * 64, &lds[(DSTB) + dl])

#define RDA(DST, BB, IB)                                                            \
    _Pragma("unroll")                                                               \
    for (int i_ = 0; i_ < 4; ++i_)                                                  \
        DST[i_] = *(const i32x4*)&lds[(BB) + (wm * 128 + ((IB) + i_) * 16) * 64 + fro];

#define RDB2(DST, BB, JB)                                                           \
    _Pragma("unroll")                                                               \
    for (int j_ = 0; j_ < 2; ++j_)                                                  \
        DST[j_] = *(const i32x4*)&lds[(BB) + 16384 + (wn * 64 + ((JB) + j_) * 16) * 64 + fro];

#define MFQ(IB, JB, AS, BS)                                                         \
    do {                                                                            \
        __builtin_amdgcn_sched_barrier(0);                                          \
        __builtin_amdgcn_s_setprio(1);                                              \
        _Pragma("unroll")                                                           \
        for (int i_ = 0; i_ < 4; ++i_)                                              \
            _Pragma("unroll")                                                       \
            for (int j_ = 0; j_ < 2; ++j_)                                          \
                acc[(IB) + i_][(JB) + j_] =                                         \
                    MFMA8(AS[i_], BS[j_], acc[(IB) + i_][(JB) + j_]);               \
        __builtin_amdgcn_s_setprio(0);                                              \
        __builtin_amdgcn_sched_barrier(0);                                          \
    } while (0)

    i32x4 acc[8][4];
#pragma unroll
    for (int i = 0; i < 8; ++i)
#pragma unroll
        for (int j = 0; j < 4; ++j) acc[i][j] = (i32x4){0, 0, 0, 0};

    i32x4 aLo[4], aHi[4], bLo[2], bHi[2];

    int cb = 0, nb = 32768, fb = 65536;

    // prologue: tiles 0,1 in canonical half order (Ah0,Bh0,Ah1,Bh1); tile 0 landed
    STG(cb + 0, Ab, 0); STG(cb + 16384, Wb, 0); STG(cb + 8192, Ab2, 0); STG(cb + 24576, Wb2, 0);
    STG(nb + 0, Ab, 1); STG(nb + 16384, Wb, 1); STG(nb + 8192, Ab2, 1); STG(nb + 24576, Wb2, 1);
    asm volatile("s_waitcnt vmcnt(4)" ::: "memory");
    __builtin_amdgcn_s_barrier();

    for (int t = 0; t < NT; ++t) {
        const int tt = (t + 2 < NT) ? (t + 2) : (NT - 1);   // clamped dummy at tail

        // ---- ph0: read aLo,bLo(t); stage Ah0(t+2) ----
        RDA(aLo, cb, 0);
        RDB2(bLo, cb, 0);
        STG(fb + 0, Ab, tt);
        __builtin_amdgcn_s_barrier();
        asm volatile("s_waitcnt lgkmcnt(0)" ::: "memory");
        MFQ(0, 0, aLo, bLo);

        // ---- ph1: read aHi(t); stage Bh0(t+2) ----
        RDA(aHi, cb, 4);
        STG(fb + 16384, Wb, tt);
        __builtin_amdgcn_s_barrier();
        asm volatile("s_waitcnt lgkmcnt(0)" ::: "memory");
        MFQ(4, 0, aHi, bLo);

        // ---- ph2: read bHi(t); stage Ah1(t+2) ----
        RDB2(bHi, cb, 2);
        STG(fb + 8192, Ab2, tt);
        __builtin_amdgcn_s_barrier();
        asm volatile("s_waitcnt lgkmcnt(0)" ::: "memory");
        MFQ(0, 2, aLo, bHi);

        // ---- ph3: stage Bh1(t+2); counted vmcnt -> tile t+1 landed ----
        STG(fb + 24576, Wb2, tt);
        asm volatile("s_waitcnt vmcnt(4)" ::: "memory");
        __builtin_amdgcn_s_barrier();
        MFQ(4, 2, aHi, bHi);

        const int tb = cb; cb = nb; nb = fb; fb = tb;
    }
#undef STG
#undef RDA
#undef RDB2
#undef MFQ

    // epilogue: D mapping col=lane&15, row=(lane>>4)*4+reg (m89-verified)
    const long rowA0 = (long)bm * 256 + wm * 128;
    const int  colB0 = bn * 256 + wn * 64;
    float scj[4];
#pragma unroll
    for (int j = 0; j < 4; ++j) scj[j] = scale[colB0 + j * 16 + l15];
#pragma unroll
    for (int i = 0; i < 8; ++i) {
        const long rbase = rowA0 + i * 16 + c16 * 4;
        const float4 s4 = *(const float4*)(sx + rbase);
#pragma unroll
        for (int j = 0; j < 4; ++j) {
            float* cp = C + rbase * NDIM + colB0 + j * 16 + l15;
            cp[0 * (long)NDIM] = (float)acc[i][j][0] * scj[j] * s4.x;
            cp[1 * (long)NDIM] = (float)acc[i][j][1] * scj[j] * s4.y;
            cp[2 * (long)NDIM] = (float)acc[i][j][2] * scj[j] * s4.z;
            cp[3 * (long)NDIM] = (float)acc[i][j][3] * scj[j] * s4.w;
        }
    }
}

// ---------------- safety fallback (no workspace needed, fp32, slow) ----------------

__global__ __launch_bounds__(256)
void fallback_kernel(const float* __restrict__ x, const int* __restrict__ q,
                     const float* __restrict__ scale, const int* __restrict__ zp,
                     float* __restrict__ out) {
    __shared__ float sA[64][17];
    __shared__ float sB[64][17];
    const int bn = (int)blockIdx.x % (NDIM / 64);
    const int bm = (int)blockIdx.x / (NDIM / 64);
    const int t  = threadIdx.x;
    const int tx = t & 15, ty = t >> 4;
    const long rowA = (long)bm * 64, rowB = (long)bn * 64;
    float acc[4][4] = {};
    for (int k0 = 0; k0 < KDIM; k0 += 16) {
#pragma unroll
        for (int i = 0; i < 4; ++i) {
            const int e = t + i * 256;
            const int r = e >> 4, c = e & 15;
            sA[r][c] = x[(rowA + r) * KDIM + k0 + c];
            const int o = (int)rowB + r;
            sB[r][c] = (float)(q[(long)o * KDIM + k0 + c] - zp[o]) * scale[o];
        }
        __syncthreads();
#pragma unroll
        for (int kk = 0; kk < 16; ++kk) {
            float a[4], b[4];
#pragma unroll
            for (int i = 0; i < 4; ++i) a[i] = sA[ty * 4 + i][kk];
#pragma unroll
            for (int j = 0; j < 4; ++j) b[j] = sB[tx * 4 + j][kk];
#pragma unroll
            for (int i = 0; i < 4; ++i)
#pragma unroll
                for (int j = 0; j < 4; ++j) acc[i][j] += a[i] * b[j];
        }
        __syncthreads();
    }
#pragma unroll
    for (int i = 0; i < 4; ++i) {
        const long r = rowA + ty * 4 + i;
#pragma unroll
        for (int j = 0; j < 4; ++j)
            out[r * NDIM + rowB + tx * 4 + j] = acc[i][j];
    }
}

// ---------------- launch ----------------

extern "C" void kernel_launch(void* const* d_in, const int* in_sizes, int n_in,
                              void* d_out, int out_size, void* d_ws, size_t ws_size,
                              hipStream_t stream) {
    const float* x     = (const float*)d_in[0];
    const int*   qw    = (const int*)d_in[1];
    const float* scale = (const float*)d_in[2];
    const int*   zp    = (const int*)d_in[3];
    float*       out   = (float*)d_out;

    const size_t needA  = (size_t)MDIM * KDIM;          // 33.5 MB int8
    const size_t needW  = (size_t)NDIM * KDIM;          // 67.1 MB int8
    const size_t needSx = (size_t)MDIM * sizeof(float); // 32 KB

    if (ws_size >= needA + needW + needSx) {
        int8_t* xq = (int8_t*)d_ws;
        int8_t* wq = xq + needA;
        float*  sx = (float*)((char*)d_ws + needA + needW);
        quant_x_kernel<<<MDIM, 256, 0, stream>>>(x, xq, sx);
        quant_w_kernel<<<(NDIM * (KDIM / 16)) / 256, 256, 0, stream>>>(qw, zp, wq);
        gemm_i8_kernel<<<(MDIM / 256) * (NDIM / 256), 512, 0, stream>>>(xq, wq, scale, sx, out);
    } else {
        fallback_kernel<<<(MDIM / 64) * (NDIM / 64), 256, 0, stream>>>(x, qw, scale, zp, out);
    }
}